// Round 2
// baseline (410.492 us; speedup 1.0000x reference)
//
#include <hip/hip_runtime.h>

#define S_LEN 2048
#define DMODEL 768
#define NH 12
#define DHEAD 64
#define BATCH 4
#define MROWS (BATCH * S_LEN)  // 8192
#define NQKV 2304              // 3*DMODEL
#define LOG2E 1.4426950408889634f

using short8 = __attribute__((ext_vector_type(8))) short;
using f32x4  = __attribute__((ext_vector_type(4))) float;
using f32x16 = __attribute__((ext_vector_type(16))) float;

typedef const __attribute__((address_space(1))) void* gas_ptr;
typedef __attribute__((address_space(3))) void* las_ptr;

__device__ __forceinline__ void gl2lds16(const void* g, void* l) {
  __builtin_amdgcn_global_load_lds((gas_ptr)(unsigned long long)g,
                                   (las_ptr)(unsigned int)(unsigned long long)l,
                                   16, 0, 0);
}

// 2^x via raw v_exp_f32
__device__ __forceinline__ float fexp2(float x) {
  float r;
  asm("v_exp_f32 %0, %1" : "=v"(r) : "v"(x));
  return r;
}

// packed f32x2 -> bf16x2 (RNE), lo in [15:0]
__device__ __forceinline__ unsigned cvtpk(float lo, float hi) {
  unsigned r;
  asm("v_cvt_pk_bf16_f32 %0, %1, %2" : "=v"(r) : "v"(lo), "v"(hi));
  return r;
}

// swap a.hi32lanes <-> b.lo32lanes
__device__ __forceinline__ void plswap(unsigned &a, unsigned &b) {
  asm("v_permlane32_swap_b32 %0, %1" : "+v"(a), "+v"(b));
}

// inline-asm LDS reads: opaque to the compiler's waitcnt pass (rule #18 pattern)
__device__ __forceinline__ short8 lds_read_s8(unsigned a) {
  short8 r; asm volatile("ds_read_b128 %0, %1" : "=v"(r) : "v"(a)); return r;
}
__device__ __forceinline__ f32x4 lds_read_f4(unsigned a) {
  f32x4 r; asm volatile("ds_read_b128 %0, %1" : "=v"(r) : "v"(a)); return r;
}
__device__ __forceinline__ unsigned lofs(const void* p) {
  return (unsigned)(unsigned long long)p;
}

#define SWAIT(cnt) do { asm volatile("s_waitcnt " cnt); \
  __builtin_amdgcn_sched_barrier(0); } while (0)

// Fused prep: fp32->bf16 for X and the 3 W's, mask -> (mask-10)*log2e
__global__ __launch_bounds__(256) void prep_kernel(
    const float* __restrict__ hs, const float* __restrict__ Wq,
    const float* __restrict__ Wk, const float* __restrict__ Wv,
    const float* __restrict__ mask,
    unsigned short* __restrict__ Xb, unsigned short* __restrict__ Wall,
    float* __restrict__ mask2)
{
  const int NX = MROWS * DMODEL / 4;
  const int NW = DMODEL * DMODEL / 4;
  const int NM = (BATCH * S_LEN) / 4;
  int i = blockIdx.x * 256 + threadIdx.x;
  if (i < NX) {
    float4 f = ((const float4*)hs)[i];
    uint2 o = { cvtpk(f.x, f.y), cvtpk(f.z, f.w) };
    ((uint2*)Xb)[i] = o;
  } else if (i < NX + 3 * NW) {
    int j = i - NX;
    int sec = j / NW, r = j - sec * NW;
    const float* src = (sec == 0) ? Wq : (sec == 1) ? Wk : Wv;
    float4 f = ((const float4*)src)[r];
    uint2 o = { cvtpk(f.x, f.y), cvtpk(f.z, f.w) };
    ((uint2*)(Wall + (size_t)sec * DMODEL * DMODEL))[r] = o;
  } else if (i < NX + 3 * NW + NM) {
    int r = i - NX - 3 * NW;
    float4 m = ((const float4*)mask)[r];
    float4 o = { (m.x - 10.f) * LOG2E, (m.y - 10.f) * LOG2E,
                 (m.z - 10.f) * LOG2E, (m.w - 10.f) * LOG2E };
    ((float4*)mask2)[r] = o;
  }
}

// Out[m,n] = sum_k X[m,k]*Wall[n,k] + bias(n); Q section pre-scaled 1/8*log2e.
__global__ __launch_bounds__(256) void qkv_gemm(
    const unsigned short* __restrict__ Xb,   // [8192][768]
    const unsigned short* __restrict__ Wall, // [2304][768]
    const float* __restrict__ bq,
    const float* __restrict__ bk,
    const float* __restrict__ bv,
    unsigned short* __restrict__ Out)        // [8192][2304]
{
  __shared__ __align__(16) short As[128][64];
  __shared__ __align__(16) short Bs[128][64];

  int m0 = blockIdx.y * 128;
  int n0 = blockIdx.x * 128;
  int t = threadIdx.x;
  int w = t >> 6, lane = t & 63, lg = lane >> 4, lc = lane & 15;
  int wr = (w >> 1) * 64, wc = (w & 1) * 64;

  int srow = lane >> 3;
  int schunk = (lane & 7) ^ srow;

  f32x4 acc[4][4] = {};

  for (int k0 = 0; k0 < DMODEL; k0 += 64) {
    __syncthreads();
    for (int it = 0; it < 4; ++it) {
      int rb = w * 32 + it * 8;
      int r = rb + srow;
      gl2lds16(&Xb[(size_t)(m0 + r) * DMODEL + k0 + schunk * 8], &As[rb][0]);
      gl2lds16(&Wall[(size_t)(n0 + r) * DMODEL + k0 + schunk * 8], &Bs[rb][0]);
    }
    __syncthreads();
    for (int ks = 0; ks < 2; ++ks) {
      short8 a[4], b[4];
      for (int mt = 0; mt < 4; ++mt)
        a[mt] = *(const short8*)&As[wr + mt * 16 + lc][(((ks * 4 + lg) ^ (lc & 7))) * 8];
      for (int nt = 0; nt < 4; ++nt)
        b[nt] = *(const short8*)&Bs[wc + nt * 16 + lc][(((ks * 4 + lg) ^ (lc & 7))) * 8];
      for (int mt = 0; mt < 4; ++mt)
        for (int nt = 0; nt < 4; ++nt)
          acc[mt][nt] = __builtin_amdgcn_mfma_f32_16x16x32_bf16(a[mt], b[nt], acc[mt][nt], 0, 0, 0);
    }
  }

  for (int nt = 0; nt < 4; ++nt) {
    int col = n0 + wc + nt * 16 + lc;
    float bb = (col < 768) ? bq[col] : (col < 1536) ? bk[col - 768] : bv[col - 1536];
    float sc = (col < 768) ? (0.125f * LOG2E) : 1.0f;
    for (int mt = 0; mt < 4; ++mt) {
      int row = m0 + wr + mt * 16 + lg * 4;
      for (int i = 0; i < 4; ++i) {
        float v = (acc[mt][nt][i] + bb) * sc;
        Out[(size_t)(row + i) * NQKV + col] = (unsigned short)cvtpk(v, v);
      }
    }
  }
}

// V section of QKV -> Vt [b][h][d][s]
__global__ __launch_bounds__(256) void v_transpose(
    const unsigned short* __restrict__ QKV,
    unsigned short* __restrict__ Vt)
{
  int st = blockIdx.x, h = blockIdx.y, b = blockIdx.z;
  __shared__ __align__(16) short Ls[64][72];
  int t = threadIdx.x;
  int s0 = st * 64;
  int lr = t >> 3, ls = (t & 7) * 8;
  for (int it = 0; it < 2; ++it) {
    int r = lr + it * 32;
    *(int4*)&Ls[r][ls] =
        *(const int4*)&QKV[(size_t)(b * S_LEN + s0 + r) * NQKV + 1536 + h * DHEAD + ls];
  }
  __syncthreads();
  int d = t & 63, sq = t >> 6;
  size_t obase = ((size_t)((b * NH + h) * DHEAD + d)) * S_LEN + s0;
  for (int it = 0; it < 2; ++it) {
    int ss = sq + it * 4;
    short8 vv;
    for (int j = 0; j < 8; ++j) vv[j] = Ls[ss * 8 + j][d];
    *(short8*)&Vt[obase + ss * 8] = vv;
  }
}

// Flash attention, 32x32x16 MFMA, fixed-max softmax (base-2 domain).
// Raw s_barrier + asm ds_read/lgkmcnt discipline; static 2x-unrolled dbuf;
// mask row in LDS; P in registers via cvt_pk + permlane32_swap.
__global__ __launch_bounds__(256, 3) void flash_attn(
    const unsigned short* __restrict__ QKV,  // [8192][2304]; Q pre-scaled log2e/8
    const unsigned short* __restrict__ Vt,   // [48*64][2048]
    const float* __restrict__ mask2,         // (mask-10)*log2e, [B][S]
    float* __restrict__ out)                 // [B][S][768]
{
  int qt = blockIdx.x, h = blockIdx.y, b = blockIdx.z;
  __shared__ __align__(16) short Ks0[64][64], Ks1[64][64];   // swizzled [key][d]
  __shared__ __align__(16) short Vts0[64][64], Vts1[64][64]; // swizzled [d][key]
  __shared__ __align__(16) float Ms[S_LEN];                  // mask row, 8KB

  int t = threadIdx.x, w = t >> 6, lane = t & 63;
  int m31 = lane & 31, hf = lane >> 5;
  int q0 = qt * 128;
  int srow = lane >> 3;
  int schunk = (lane & 7) ^ srow;

  size_t vtbase = (size_t)((b * NH + h) * DHEAD) * S_LEN;
  size_t kbase0 = (size_t)(b * S_LEN) * NQKV + 768 + h * DHEAD;
  const float* mrow = mask2 + (size_t)b * S_LEN;

  // Q B-frags: loop-invariant, direct from global. B[k=d][n=q]: n=m31, k=8*hf+j
  short8 qf[4];
  {
    size_t qrow = (size_t)(b * S_LEN + q0 + w * 32 + m31) * NQKV + h * DHEAD;
#pragma unroll
    for (int kk = 0; kk < 4; ++kk)
      qf[kk] = *(const short8*)&QKV[qrow + kk * 16 + hf * 8];
  }

  // stage mask row -> LDS (each wave: 2x 1KB chunks)
#pragma unroll
  for (int it = 0; it < 2; ++it) {
    int c = w * 2 + it;
    gl2lds16(&mrow[c * 256 + lane * 4], &Ms[c * 256]);
  }
  // stage tile 0 -> Ks0/Vts0
#pragma unroll
  for (int it = 0; it < 2; ++it) {
    int rb = w * 16 + it * 8;
    int r = rb + srow;
    gl2lds16(&QKV[kbase0 + (size_t)r * NQKV + schunk * 8], &Ks0[rb][0]);
    gl2lds16(&Vt[vtbase + (size_t)r * S_LEN + schunk * 8], &Vts0[rb][0]);
  }
  SWAIT("vmcnt(0)");
  __builtin_amdgcn_s_barrier();
  __builtin_amdgcn_sched_barrier(0);
  // force qf's vmcnt wait to resolve here (not conservatively inside the loop)
#pragma unroll
  for (int kk = 0; kk < 4; ++kk) asm volatile("" :: "v"(qf[kk]));

  float lsumA = 0.f, lsumB = 0.f;
  f32x16 o[2] = {};
  const f32x16 Zv = {};  // persistent zero C-operand for first QK MFMA

  auto step = [&](auto& KC, auto& VC, auto& KN, auto& VN, int kt) {
    int k0 = kt * 64;
    // ---- top sync: tile kt fully landed (own loads) + published (barrier) ----
    SWAIT("vmcnt(0)");
    __builtin_amdgcn_s_barrier();
    __builtin_amdgcn_sched_barrier(0);

    // ---- prefetch tile kt+1 -> KN/VN (readers of those buffers are done) ----
    {
      int ktn = (kt + 1 < S_LEN / 64) ? kt + 1 : kt;
      int k0n = ktn * 64;
#pragma unroll
      for (int it = 0; it < 2; ++it) {
        int rb = w * 16 + it * 8;
        int r = rb + srow;
        gl2lds16(&QKV[kbase0 + (size_t)(k0n + r) * NQKV + schunk * 8], &KN[rb][0]);
        gl2lds16(&Vt[vtbase + (size_t)r * S_LEN + k0n + schunk * 8], &VN[rb][0]);
      }
    }

    // ---- issue K reads (8) then mask reads (8) ----
    short8 ak[8];
#pragma unroll
    for (int kk = 0; kk < 4; ++kk)
#pragma unroll
      for (int mt = 0; mt < 2; ++mt)
        ak[kk * 2 + mt] =
            lds_read_s8(lofs(&KC[mt * 32 + m31][((kk * 2 + hf) ^ (m31 & 7)) * 8]));
    f32x4 mre[8];
#pragma unroll
    for (int mt = 0; mt < 2; ++mt)
#pragma unroll
      for (int g = 0; g < 4; ++g)
        mre[mt * 4 + g] = lds_read_f4(lofs(&Ms[k0 + mt * 32 + g * 8 + hf * 4]));

    SWAIT("lgkmcnt(8)");  // K landed (mask still in flight)

    // ---- QK^T MFMAs ----
    __builtin_amdgcn_s_setprio(1);
    f32x16 s0v = __builtin_amdgcn_mfma_f32_32x32x16_bf16(ak[0], qf[0], Zv, 0, 0, 0);
    f32x16 s1v = __builtin_amdgcn_mfma_f32_32x32x16_bf16(ak[1], qf[0], Zv, 0, 0, 0);
#pragma unroll
    for (int kk = 1; kk < 4; ++kk) {
      s0v = __builtin_amdgcn_mfma_f32_32x32x16_bf16(ak[kk * 2 + 0], qf[kk], s0v, 0, 0, 0);
      s1v = __builtin_amdgcn_mfma_f32_32x32x16_bf16(ak[kk * 2 + 1], qf[kk], s1v, 0, 0, 0);
    }
    __builtin_amdgcn_s_setprio(0);

    // ---- issue V reads (8); latency hides under softmax ----
    short8 vb[8];
#pragma unroll
    for (int kk = 0; kk < 4; ++kk)
#pragma unroll
      for (int nt = 0; nt < 2; ++nt)
        vb[kk * 2 + nt] =
            lds_read_s8(lofs(&VC[nt * 32 + m31][((kk * 2 + hf) ^ (m31 & 7)) * 8]));

    SWAIT("lgkmcnt(8)");  // mask landed (V still in flight)

    // ---- softmax: p = 2^(s + m); pack bf16 pairs ----
    unsigned pw[2][4][2];
#pragma unroll
    for (int mt = 0; mt < 2; ++mt) {
      const f32x16& sv = mt ? s1v : s0v;
#pragma unroll
      for (int g = 0; g < 4; ++g) {
        f32x4 mv = mre[mt * 4 + g];
        float p0 = fexp2(sv[g * 4 + 0] + mv[0]);
        float p1 = fexp2(sv[g * 4 + 1] + mv[1]);
        float p2 = fexp2(sv[g * 4 + 2] + mv[2]);
        float p3 = fexp2(sv[g * 4 + 3] + mv[3]);
        lsumA += p0 + p1;
        lsumB += p2 + p3;
        pw[mt][g][0] = cvtpk(p0, p1);
        pw[mt][g][1] = cvtpk(p2, p3);
      }
    }

    // ---- build PV A-frags via permlane32_swap ----
    short8 fr[4];
#pragma unroll
    for (int mt = 0; mt < 2; ++mt)
#pragma unroll
      for (int kk2 = 0; kk2 < 2; ++kk2) {
        unsigned a0 = pw[mt][2 * kk2][0], b0 = pw[mt][2 * kk2 + 1][0];
        unsigned a1 = pw[mt][2 * kk2][1], b1 = pw[mt][2 * kk2 + 1][1];
        plswap(a0, b0);
        plswap(a1, b1);
        union { unsigned u[4]; short8 v; } u_;
        u_.u[0] = a0; u_.u[1] = a1; u_.u[2] = b0; u_.u[3] = b1;
        fr[mt * 2 + kk2] = u_.v;
      }

    SWAIT("lgkmcnt(0)");  // V landed

    // ---- PV MFMAs ----
    __builtin_amdgcn_s_setprio(1);
#pragma unroll
    for (int kk = 0; kk < 4; ++kk) {
      o[0] = __builtin_amdgcn_mfma_f32_32x32x16_bf16(fr[kk], vb[kk * 2 + 0], o[0], 0, 0, 0);
      o[1] = __builtin_amdgcn_mfma_f32_32x32x16_bf16(fr[kk], vb[kk * 2 + 1], o[1], 0, 0, 0);
    }
    __builtin_amdgcn_s_setprio(0);
  };

#pragma unroll 1
  for (int i2 = 0; i2 < S_LEN / 128; ++i2) {
    step(Ks0, Vts0, Ks1, Vts1, 2 * i2);
    step(Ks1, Vts1, Ks0, Vts0, 2 * i2 + 1);
  }

  // final l for q=m31: own half + partner half, once
  float lsum = lsumA + lsumB;
  lsum += __shfl_xor(lsum, 32, 64);
  float inv = 1.0f / lsum;
  // broadcast inv to C-layout rows: row q = (r&3) + 8*(r>>2) + 4*hf
  float lv[16];
#pragma unroll
  for (int r = 0; r < 16; ++r)
    lv[r] = __shfl(inv, (r & 3) + 8 * (r >> 2) + 4 * hf, 64);

  for (int nt = 0; nt < 2; ++nt)
    for (int r = 0; r < 16; ++r) {
      int qrow = (r & 3) + 8 * (r >> 2) + 4 * hf;
      int q = q0 + w * 32 + qrow;
      out[(size_t)(b * S_LEN + q) * DMODEL + h * DHEAD + nt * 32 + m31] = o[nt][r] * lv[r];
    }
}

extern "C" void kernel_launch(void* const* d_in, const int* in_sizes, int n_in,
                              void* d_out, int out_size, void* d_ws, size_t ws_size,
                              hipStream_t stream) {
  const float* hs   = (const float*)d_in[0];
  const float* mask = (const float*)d_in[1];
  const float* Wq   = (const float*)d_in[2];
  const float* bq   = (const float*)d_in[3];
  const float* Wk   = (const float*)d_in[4];
  const float* bk   = (const float*)d_in[5];
  const float* Wv   = (const float*)d_in[6];
  const float* bv   = (const float*)d_in[7];
  float* out = (float*)d_out;

  char* ws = (char*)d_ws;
  const size_t XB_BYTES   = (size_t)MROWS * DMODEL * 2;
  const size_t QKV_BYTES  = (size_t)MROWS * NQKV * 2;
  const size_t WALL_BYTES = (size_t)NQKV * DMODEL * 2;
  unsigned short* Xb    = (unsigned short*)ws;
  unsigned short* QKV   = (unsigned short*)(ws + XB_BYTES);
  unsigned short* Wall  = (unsigned short*)(ws + XB_BYTES + QKV_BYTES);
  float*          mask2 = (float*)(ws + XB_BYTES + QKV_BYTES + WALL_BYTES);
  unsigned short* Vtg   = Xb;  // Xb dead after qkv_gemm

  const int NX = MROWS * DMODEL / 4;
  const int NW = DMODEL * DMODEL / 4;
  const int NM = (BATCH * S_LEN) / 4;
  int nprep = NX + 3 * NW + NM;
  prep_kernel<<<(nprep + 255) / 256, 256, 0, stream>>>(hs, Wq, Wk, Wv, mask, Xb, Wall, mask2);

  qkv_gemm<<<dim3(NQKV / 128, MROWS / 128), 256, 0, stream>>>(Xb, Wall, bq, bk, bv, QKV);

  v_transpose<<<dim3(S_LEN / 64, NH, BATCH), 256, 0, stream>>>(QKV, Vtg);

  flash_attn<<<dim3(S_LEN / 128, NH, BATCH), 256, 0, stream>>>(QKV, Vtg, mask2, out);
}

// Round 4
// 252.129 us; speedup vs baseline: 1.6281x; 1.6281x over previous
//
#include <hip/hip_runtime.h>

#define S_LEN 2048
#define DMODEL 768
#define NH 12
#define DHEAD 64
#define BATCH 4
#define MROWS (BATCH * S_LEN)  // 8192
#define NQKV 2304              // 3*DMODEL
#define LOG2E 1.4426950408889634f

using short8 = __attribute__((ext_vector_type(8))) short;
using f32x4  = __attribute__((ext_vector_type(4))) float;
using f32x16 = __attribute__((ext_vector_type(16))) float;

typedef const __attribute__((address_space(1))) void* gas_ptr;
typedef __attribute__((address_space(3))) void* las_ptr;

__device__ __forceinline__ void gl2lds16(const void* g, void* l) {
  __builtin_amdgcn_global_load_lds((gas_ptr)(unsigned long long)g,
                                   (las_ptr)(unsigned int)(unsigned long long)l,
                                   16, 0, 0);
}

// 2^x via raw v_exp_f32
__device__ __forceinline__ float fexp2(float x) {
  float r;
  asm("v_exp_f32 %0, %1" : "=v"(r) : "v"(x));
  return r;
}

// packed f32x2 -> bf16x2 (RNE), lo in [15:0]
__device__ __forceinline__ unsigned cvtpk(float lo, float hi) {
  unsigned r;
  asm("v_cvt_pk_bf16_f32 %0, %1, %2" : "=v"(r) : "v"(lo), "v"(hi));
  return r;
}

// swap a.hi32lanes <-> b.lo32lanes
__device__ __forceinline__ void plswap(unsigned &a, unsigned &b) {
  asm("v_permlane32_swap_b32 %0, %1" : "+v"(a), "+v"(b));
}

// Fused prep: fp32->bf16 for X and the 3 W's, mask -> (mask-10)*log2e
__global__ __launch_bounds__(256) void prep_kernel(
    const float* __restrict__ hs, const float* __restrict__ Wq,
    const float* __restrict__ Wk, const float* __restrict__ Wv,
    const float* __restrict__ mask,
    unsigned short* __restrict__ Xb, unsigned short* __restrict__ Wall,
    float* __restrict__ mask2)
{
  const int NX = MROWS * DMODEL / 4;
  const int NW = DMODEL * DMODEL / 4;
  const int NM = (BATCH * S_LEN) / 4;
  int i = blockIdx.x * 256 + threadIdx.x;
  if (i < NX) {
    float4 f = ((const float4*)hs)[i];
    uint2 o = { cvtpk(f.x, f.y), cvtpk(f.z, f.w) };
    ((uint2*)Xb)[i] = o;
  } else if (i < NX + 3 * NW) {
    int j = i - NX;
    int sec = j / NW, r = j - sec * NW;
    const float* src = (sec == 0) ? Wq : (sec == 1) ? Wk : Wv;
    float4 f = ((const float4*)src)[r];
    uint2 o = { cvtpk(f.x, f.y), cvtpk(f.z, f.w) };
    ((uint2*)(Wall + (size_t)sec * DMODEL * DMODEL))[r] = o;
  } else if (i < NX + 3 * NW + NM) {
    int r = i - NX - 3 * NW;
    float4 m = ((const float4*)mask)[r];
    float4 o = { (m.x - 10.f) * LOG2E, (m.y - 10.f) * LOG2E,
                 (m.z - 10.f) * LOG2E, (m.w - 10.f) * LOG2E };
    ((float4*)mask2)[r] = o;
  }
}

// Out[m,n] = sum_k X[m,k]*Wall[n,k] + bias(n); Q section pre-scaled 1/8*log2e.
// XCD-swizzled 1-D grid: m-panels clustered per XCD so each XCD's L2 holds
// one 8-tile A band (1.6MB) + the whole B (3.5MB) instead of ~all of A.
__global__ __launch_bounds__(256) void qkv_gemm(
    const unsigned short* __restrict__ Xb,   // [8192][768]
    const unsigned short* __restrict__ Wall, // [2304][768]
    const float* __restrict__ bq,
    const float* __restrict__ bk,
    const float* __restrict__ bv,
    unsigned short* __restrict__ Out)        // [8192][2304]
{
  __shared__ __align__(16) short As[128][64];
  __shared__ __align__(16) short Bs[128][64];

  // grid = 1152 = 8 xcd * 8 mlocal * 18 n
  int gid = blockIdx.x;
  int x = gid & 7;          // xcd (round-robin dispatch)
  int j = gid >> 3;         // 0..143
  int mloc = j / 18;        // 0..7
  int ntile = j - mloc * 18;
  int m0 = (x * 8 + mloc) * 128;
  int n0 = ntile * 128;

  int t = threadIdx.x;
  int w = t >> 6, lane = t & 63, lg = lane >> 4, lc = lane & 15;
  int wr = (w >> 1) * 64, wc = (w & 1) * 64;

  int srow = lane >> 3;
  int schunk = (lane & 7) ^ srow;

  f32x4 acc[4][4] = {};

  for (int k0 = 0; k0 < DMODEL; k0 += 64) {
    __syncthreads();
    for (int it = 0; it < 4; ++it) {
      int rb = w * 32 + it * 8;
      int r = rb + srow;
      gl2lds16(&Xb[(size_t)(m0 + r) * DMODEL + k0 + schunk * 8], &As[rb][0]);
      gl2lds16(&Wall[(size_t)(n0 + r) * DMODEL + k0 + schunk * 8], &Bs[rb][0]);
    }
    __syncthreads();
    for (int ks = 0; ks < 2; ++ks) {
      short8 a[4], b[4];
      for (int mt = 0; mt < 4; ++mt)
        a[mt] = *(const short8*)&As[wr + mt * 16 + lc][(((ks * 4 + lg) ^ (lc & 7))) * 8];
      for (int nt = 0; nt < 4; ++nt)
        b[nt] = *(const short8*)&Bs[wc + nt * 16 + lc][(((ks * 4 + lg) ^ (lc & 7))) * 8];
      for (int mt = 0; mt < 4; ++mt)
        for (int nt = 0; nt < 4; ++nt)
          acc[mt][nt] = __builtin_amdgcn_mfma_f32_16x16x32_bf16(a[mt], b[nt], acc[mt][nt], 0, 0, 0);
    }
  }

  for (int nt = 0; nt < 4; ++nt) {
    int col = n0 + wc + nt * 16 + lc;
    float bb = (col < 768) ? bq[col] : (col < 1536) ? bk[col - 768] : bv[col - 1536];
    float sc = (col < 768) ? (0.125f * LOG2E) : 1.0f;
    for (int mt = 0; mt < 4; ++mt) {
      int row = m0 + wr + mt * 16 + lg * 4;
      for (int i = 0; i < 4; ++i) {
        float v = (acc[mt][nt][i] + bb) * sc;
        Out[(size_t)(row + i) * NQKV + col] = (unsigned short)cvtpk(v, v);
      }
    }
  }
}

// V section of QKV -> Vt [b][h][d][s]
__global__ __launch_bounds__(256) void v_transpose(
    const unsigned short* __restrict__ QKV,
    unsigned short* __restrict__ Vt)
{
  int st = blockIdx.x, h = blockIdx.y, b = blockIdx.z;
  __shared__ __align__(16) short Ls[64][72];
  int t = threadIdx.x;
  int s0 = st * 64;
  int lr = t >> 3, ls = (t & 7) * 8;
  for (int it = 0; it < 2; ++it) {
    int r = lr + it * 32;
    *(int4*)&Ls[r][ls] =
        *(const int4*)&QKV[(size_t)(b * S_LEN + s0 + r) * NQKV + 1536 + h * DHEAD + ls];
  }
  __syncthreads();
  int d = t & 63, sq = t >> 6;
  size_t obase = ((size_t)((b * NH + h) * DHEAD + d)) * S_LEN + s0;
  for (int it = 0; it < 2; ++it) {
    int ss = sq + it * 4;
    short8 vv;
    for (int j = 0; j < 8; ++j) vv[j] = Ls[ss * 8 + j][d];
    *(short8*)&Vt[obase + ss * 8] = vv;
  }
}

// Flash attention, 32x32x16 MFMA, fixed-max softmax (base-2 domain).
// Verified 94us compute structure + two fixes:
//  1) mask loads hoisted BEFORE the prefetch issue (vmcnt FIFO: their auto-wait
//     no longer drains the in-flight prefetch at softmax start)
//  2) XCD-swizzled 1-D grid: all 16 q-blocks of one (b,h) on one XCD ->
//     per-XCD K/V working set ~3MB, L2-resident.
__global__ __launch_bounds__(256, 4) void flash_attn(
    const unsigned short* __restrict__ QKV,  // [8192][2304]; Q pre-scaled log2e/8
    const unsigned short* __restrict__ Vt,   // [48*64][2048]
    const float* __restrict__ mask2,         // (mask-10)*log2e, [B][S]
    float* __restrict__ out)                 // [B][S][768]
{
  // grid = 768 = 8 xcd * 6 glocal * 16 qt ; group g=(b,h) pinned to one xcd
  int gid = blockIdx.x;
  int x = gid & 7;          // xcd
  int j = gid >> 3;         // 0..95
  int gloc = j >> 4;        // 0..5
  int qt = j & 15;
  int g = gloc * 8 + x;     // 0..47
  int h = g % NH;
  int b = g / NH;

  __shared__ __align__(16) short Ks[2][64][64];    // swizzled [key][d]
  __shared__ __align__(16) short Vts[2][64][64];   // swizzled [d][key]

  int t = threadIdx.x, w = t >> 6, lane = t & 63;
  int m31 = lane & 31, hf = lane >> 5;
  int q0 = qt * 128;
  int srow = lane >> 3;
  int schunk = (lane & 7) ^ srow;

  size_t vtbase = (size_t)((b * NH + h) * DHEAD) * S_LEN;
  size_t kbase0 = (size_t)(b * S_LEN) * NQKV + 768 + h * DHEAD;
  const float* mrow = mask2 + (size_t)b * S_LEN;

  // Q B-frags: loop-invariant, direct from global. B[k=d][n=q]: n=m31, k=8*hf+j
  short8 qf[4];
  {
    size_t qrow = (size_t)(b * S_LEN + q0 + w * 32 + m31) * NQKV + h * DHEAD;
#pragma unroll
    for (int kk = 0; kk < 4; ++kk)
      qf[kk] = *(const short8*)&QKV[qrow + kk * 16 + hf * 8];
  }

  float lsum = 0.f;
  f32x16 o[2] = {};

  // prologue: stage tile 0 into buffer 0
#pragma unroll
  for (int it = 0; it < 2; ++it) {
    int rb = w * 16 + it * 8;
    int r = rb + srow;
    gl2lds16(&QKV[kbase0 + (size_t)r * NQKV + schunk * 8], &Ks[0][rb][0]);
    gl2lds16(&Vt[vtbase + (size_t)r * S_LEN + schunk * 8], &Vts[0][rb][0]);
  }

  int buf = 0;
#pragma unroll 1
  for (int kt = 0; kt < S_LEN / 64; ++kt) {
    int k0 = kt * 64;
    __syncthreads();  // drains prev prefetch (this tile's data) + publishes

    // ---- mask loads FIRST (older than prefetch in the vmcnt FIFO) ----
    f32x4 mv_[8];
#pragma unroll
    for (int mt = 0; mt < 2; ++mt)
#pragma unroll
      for (int gg = 0; gg < 4; ++gg)
        mv_[mt * 4 + gg] = *(const f32x4*)&mrow[k0 + mt * 32 + gg * 8 + hf * 4];
    __builtin_amdgcn_sched_barrier(0);

    // ---- prefetch next tile into buf^1 (clamped redundant reload at end) ----
    {
      int ktn = (kt + 1 < S_LEN / 64) ? (kt + 1) : kt;
      int k0n = ktn * 64;
#pragma unroll
      for (int it = 0; it < 2; ++it) {
        int rb = w * 16 + it * 8;
        int r = rb + srow;
        gl2lds16(&QKV[kbase0 + (size_t)(k0n + r) * NQKV + schunk * 8], &Ks[buf ^ 1][rb][0]);
        gl2lds16(&Vt[vtbase + (size_t)r * S_LEN + k0n + schunk * 8], &Vts[buf ^ 1][rb][0]);
      }
    }
    __builtin_amdgcn_sched_barrier(0);

    // ---- S^T[key][q] = K·Q^T ----
    f32x16 s[2] = {};
    __builtin_amdgcn_s_setprio(1);
#pragma unroll
    for (int kk = 0; kk < 4; ++kk)
#pragma unroll
      for (int mt = 0; mt < 2; ++mt) {
        int r = mt * 32 + m31;
        short8 ak = *(const short8*)&Ks[buf][r][((kk * 2 + hf) ^ (r & 7)) * 8];
        s[mt] = __builtin_amdgcn_mfma_f32_32x32x16_bf16(ak, qf[kk], s[mt], 0, 0, 0);
      }
    __builtin_amdgcn_s_setprio(0);

    // ---- softmax: p = 2^(s + m); mask already in registers ----
    unsigned pw[2][4][2];
#pragma unroll
    for (int mt = 0; mt < 2; ++mt)
#pragma unroll
      for (int gg = 0; gg < 4; ++gg) {
        f32x4 m4 = mv_[mt * 4 + gg];
        float p0 = fexp2(s[mt][gg * 4 + 0] + m4[0]);
        float p1 = fexp2(s[mt][gg * 4 + 1] + m4[1]);
        float p2 = fexp2(s[mt][gg * 4 + 2] + m4[2]);
        float p3 = fexp2(s[mt][gg * 4 + 3] + m4[3]);
        lsum += (p0 + p1) + (p2 + p3);
        pw[mt][gg][0] = cvtpk(p0, p1);  // keys 32mt+8g+4hf+{0,1}
        pw[mt][gg][1] = cvtpk(p2, p3);  // keys 32mt+8g+4hf+{2,3}
      }

    // ---- PV A-frags via permlane32_swap; O[q][d] += P·V ----
#pragma unroll
    for (int mt = 0; mt < 2; ++mt)
#pragma unroll
      for (int kk2 = 0; kk2 < 2; ++kk2) {
        unsigned a0 = pw[mt][2 * kk2][0], b0 = pw[mt][2 * kk2 + 1][0];
        unsigned a1 = pw[mt][2 * kk2][1], b1 = pw[mt][2 * kk2 + 1][1];
        plswap(a0, b0);
        plswap(a1, b1);
        union { unsigned u[4]; short8 v; } fr;
        fr.u[0] = a0; fr.u[1] = a1; fr.u[2] = b0; fr.u[3] = b1;
        int kk = mt * 2 + kk2;
        __builtin_amdgcn_s_setprio(1);
#pragma unroll
        for (int nt = 0; nt < 2; ++nt) {
          int r = nt * 32 + m31;
          short8 bvv = *(const short8*)&Vts[buf][r][((kk * 2 + hf) ^ (r & 7)) * 8];
          o[nt] = __builtin_amdgcn_mfma_f32_32x32x16_bf16(fr.v, bvv, o[nt], 0, 0, 0);
        }
        __builtin_amdgcn_s_setprio(0);
      }

    buf ^= 1;
  }

  // final l for q=m31: own half + partner half, once
  lsum += __shfl_xor(lsum, 32, 64);
  float inv = 1.0f / lsum;
  // broadcast inv to C-layout rows: row q = (r&3) + 8*(r>>2) + 4*hf
  float lv[16];
#pragma unroll
  for (int r = 0; r < 16; ++r)
    lv[r] = __shfl(inv, (r & 3) + 8 * (r >> 2) + 4 * hf, 64);

  for (int nt = 0; nt < 2; ++nt)
    for (int r = 0; r < 16; ++r) {
      int qrow = (r & 3) + 8 * (r >> 2) + 4 * hf;
      int q = q0 + w * 32 + qrow;
      out[(size_t)(b * S_LEN + q) * DMODEL + h * DHEAD + nt * 32 + m31] = o[nt][r] * lv[r];
    }
}

extern "C" void kernel_launch(void* const* d_in, const int* in_sizes, int n_in,
                              void* d_out, int out_size, void* d_ws, size_t ws_size,
                              hipStream_t stream) {
  const float* hs   = (const float*)d_in[0];
  const float* mask = (const float*)d_in[1];
  const float* Wq   = (const float*)d_in[2];
  const float* bq   = (const float*)d_in[3];
  const float* Wk   = (const float*)d_in[4];
  const float* bk   = (const float*)d_in[5];
  const float* Wv   = (const float*)d_in[6];
  const float* bv   = (const float*)d_in[7];
  float* out = (float*)d_out;

  char* ws = (char*)d_ws;
  const size_t XB_BYTES   = (size_t)MROWS * DMODEL * 2;
  const size_t QKV_BYTES  = (size_t)MROWS * NQKV * 2;
  const size_t WALL_BYTES = (size_t)NQKV * DMODEL * 2;
  unsigned short* Xb    = (unsigned short*)ws;
  unsigned short* QKV   = (unsigned short*)(ws + XB_BYTES);
  unsigned short* Wall  = (unsigned short*)(ws + XB_BYTES + QKV_BYTES);
  float*          mask2 = (float*)(ws + XB_BYTES + QKV_BYTES + WALL_BYTES);
  unsigned short* Vtg   = Xb;  // Xb dead after qkv_gemm

  const int NX = MROWS * DMODEL / 4;
  const int NW = DMODEL * DMODEL / 4;
  const int NM = (BATCH * S_LEN) / 4;
  int nprep = NX + 3 * NW + NM;
  prep_kernel<<<(nprep + 255) / 256, 256, 0, stream>>>(hs, Wq, Wk, Wv, mask, Xb, Wall, mask2);

  qkv_gemm<<<1152, 256, 0, stream>>>(Xb, Wall, bq, bk, bv, QKV);

  v_transpose<<<dim3(S_LEN / 64, NH, BATCH), 256, 0, stream>>>(QKV, Vtg);

  flash_attn<<<768, 256, 0, stream>>>(QKV, Vtg, mask2, out);
}

// Round 5
// 228.518 us; speedup vs baseline: 1.7963x; 1.1033x over previous
//
#include <hip/hip_runtime.h>

#define S_LEN 2048
#define DMODEL 768
#define NH 12
#define DHEAD 64
#define BATCH 4
#define MROWS (BATCH * S_LEN)  // 8192
#define NQKV 2304              // 3*DMODEL
#define LOG2E 1.4426950408889634f

using short8 = __attribute__((ext_vector_type(8))) short;
using f32x4  = __attribute__((ext_vector_type(4))) float;
using f32x16 = __attribute__((ext_vector_type(16))) float;

typedef const __attribute__((address_space(1))) void* gas_ptr;
typedef __attribute__((address_space(3))) void* las_ptr;

__device__ __forceinline__ void gl2lds16(const void* g, void* l) {
  __builtin_amdgcn_global_load_lds((gas_ptr)(unsigned long long)g,
                                   (las_ptr)(unsigned int)(unsigned long long)l,
                                   16, 0, 0);
}

// 2^x via raw v_exp_f32
__device__ __forceinline__ float fexp2(float x) {
  float r;
  asm("v_exp_f32 %0, %1" : "=v"(r) : "v"(x));
  return r;
}

// packed f32x2 -> bf16x2 (RNE), lo in [15:0]
__device__ __forceinline__ unsigned cvtpk(float lo, float hi) {
  unsigned r;
  asm("v_cvt_pk_bf16_f32 %0, %1, %2" : "=v"(r) : "v"(lo), "v"(hi));
  return r;
}

// swap a.hi32lanes <-> b.lo32lanes
__device__ __forceinline__ void plswap(unsigned &a, unsigned &b) {
  asm("v_permlane32_swap_b32 %0, %1" : "+v"(a), "+v"(b));
}

// Fused prep: fp32->bf16 for X and the 3 W's, mask -> (mask-10)*log2e
__global__ __launch_bounds__(256) void prep_kernel(
    const float* __restrict__ hs, const float* __restrict__ Wq,
    const float* __restrict__ Wk, const float* __restrict__ Wv,
    const float* __restrict__ mask,
    unsigned short* __restrict__ Xb, unsigned short* __restrict__ Wall,
    float* __restrict__ mask2)
{
  const int NX = MROWS * DMODEL / 4;
  const int NW = DMODEL * DMODEL / 4;
  const int NM = (BATCH * S_LEN) / 4;
  int i = blockIdx.x * 256 + threadIdx.x;
  if (i < NX) {
    float4 f = ((const float4*)hs)[i];
    uint2 o = { cvtpk(f.x, f.y), cvtpk(f.z, f.w) };
    ((uint2*)Xb)[i] = o;
  } else if (i < NX + 3 * NW) {
    int j = i - NX;
    int sec = j / NW, r = j - sec * NW;
    const float* src = (sec == 0) ? Wq : (sec == 1) ? Wk : Wv;
    float4 f = ((const float4*)src)[r];
    uint2 o = { cvtpk(f.x, f.y), cvtpk(f.z, f.w) };
    ((uint2*)(Wall + (size_t)sec * DMODEL * DMODEL))[r] = o;
  } else if (i < NX + 3 * NW + NM) {
    int r = i - NX - 3 * NW;
    float4 m = ((const float4*)mask)[r];
    float4 o = { (m.x - 10.f) * LOG2E, (m.y - 10.f) * LOG2E,
                 (m.z - 10.f) * LOG2E, (m.w - 10.f) * LOG2E };
    ((float4*)mask2)[r] = o;
  }
}

// Out[m,n] = sum_k X[m,k]*Wall[n,k] + bias(n); Q section pre-scaled 1/8*log2e.
// XCD-swizzled 1-D grid (benched neutral, kept).
__global__ __launch_bounds__(256) void qkv_gemm(
    const unsigned short* __restrict__ Xb,   // [8192][768]
    const unsigned short* __restrict__ Wall, // [2304][768]
    const float* __restrict__ bq,
    const float* __restrict__ bk,
    const float* __restrict__ bv,
    unsigned short* __restrict__ Out)        // [8192][2304]
{
  __shared__ __align__(16) short As[128][64];
  __shared__ __align__(16) short Bs[128][64];

  // grid = 1152 = 8 xcd * 8 mlocal * 18 n
  int gid = blockIdx.x;
  int x = gid & 7;
  int j = gid >> 3;
  int mloc = j / 18;
  int ntile = j - mloc * 18;
  int m0 = (x * 8 + mloc) * 128;
  int n0 = ntile * 128;

  int t = threadIdx.x;
  int w = t >> 6, lane = t & 63, lg = lane >> 4, lc = lane & 15;
  int wr = (w >> 1) * 64, wc = (w & 1) * 64;

  int srow = lane >> 3;
  int schunk = (lane & 7) ^ srow;

  f32x4 acc[4][4] = {};

  for (int k0 = 0; k0 < DMODEL; k0 += 64) {
    __syncthreads();
    for (int it = 0; it < 4; ++it) {
      int rb = w * 32 + it * 8;
      int r = rb + srow;
      gl2lds16(&Xb[(size_t)(m0 + r) * DMODEL + k0 + schunk * 8], &As[rb][0]);
      gl2lds16(&Wall[(size_t)(n0 + r) * DMODEL + k0 + schunk * 8], &Bs[rb][0]);
    }
    __syncthreads();
    for (int ks = 0; ks < 2; ++ks) {
      short8 a[4], b[4];
      for (int mt = 0; mt < 4; ++mt)
        a[mt] = *(const short8*)&As[wr + mt * 16 + lc][(((ks * 4 + lg) ^ (lc & 7))) * 8];
      for (int nt = 0; nt < 4; ++nt)
        b[nt] = *(const short8*)&Bs[wc + nt * 16 + lc][(((ks * 4 + lg) ^ (lc & 7))) * 8];
      for (int mt = 0; mt < 4; ++mt)
        for (int nt = 0; nt < 4; ++nt)
          acc[mt][nt] = __builtin_amdgcn_mfma_f32_16x16x32_bf16(a[mt], b[nt], acc[mt][nt], 0, 0, 0);
    }
  }

  for (int nt = 0; nt < 4; ++nt) {
    int col = n0 + wc + nt * 16 + lc;
    float bb = (col < 768) ? bq[col] : (col < 1536) ? bk[col - 768] : bv[col - 1536];
    float sc = (col < 768) ? (0.125f * LOG2E) : 1.0f;
    for (int mt = 0; mt < 4; ++mt) {
      int row = m0 + wr + mt * 16 + lg * 4;
      for (int i = 0; i < 4; ++i) {
        float v = (acc[mt][nt][i] + bb) * sc;
        Out[(size_t)(row + i) * NQKV + col] = (unsigned short)cvtpk(v, v);
      }
    }
  }
}

// V section of QKV -> Vt [b][h][d][s]
__global__ __launch_bounds__(256) void v_transpose(
    const unsigned short* __restrict__ QKV,
    unsigned short* __restrict__ Vt)
{
  int st = blockIdx.x, h = blockIdx.y, b = blockIdx.z;
  __shared__ __align__(16) short Ls[64][72];
  int t = threadIdx.x;
  int s0 = st * 64;
  int lr = t >> 3, ls = (t & 7) * 8;
  for (int it = 0; it < 2; ++it) {
    int r = lr + it * 32;
    *(int4*)&Ls[r][ls] =
        *(const int4*)&QKV[(size_t)(b * S_LEN + s0 + r) * NQKV + 1536 + h * DHEAD + ls];
  }
  __syncthreads();
  int d = t & 63, sq = t >> 6;
  size_t obase = ((size_t)((b * NH + h) * DHEAD + d)) * S_LEN + s0;
  for (int it = 0; it < 2; ++it) {
    int ss = sq + it * 4;
    short8 vv;
    for (int j = 0; j < 8; ++j) vv[j] = Ls[ss * 8 + j][d];
    *(short8*)&Vt[obase + ss * 8] = vv;
  }
}

// Flash attention — EXACT R1-benched 94us body (no fences, mask loads inside
// softmax, compiler-managed waits). Only change: 1-D XCD-swizzled grid so all
// 16 q-blocks of one (b,h) share an XCD -> K/V L2-resident (FETCH 104->24MB).
__global__ __launch_bounds__(256, 4) void flash_attn(
    const unsigned short* __restrict__ QKV,  // [8192][2304]; Q pre-scaled log2e/8
    const unsigned short* __restrict__ Vt,   // [48*64][2048]
    const float* __restrict__ mask2,         // (mask-10)*log2e, [B][S]
    float* __restrict__ out)                 // [B][S][768]
{
  // grid = 768 = 8 xcd * 6 glocal * 16 qt ; group g=(b,h) pinned to one xcd
  int gid = blockIdx.x;
  int x = gid & 7;
  int j = gid >> 3;
  int gloc = j >> 4;
  int qt = j & 15;
  int g = gloc * 8 + x;
  int h = g % NH;
  int b = g / NH;

  __shared__ __align__(16) short Ks[2][64][64];    // swizzled [key][d]
  __shared__ __align__(16) short Vts[2][64][64];   // swizzled [d][key]

  int t = threadIdx.x, w = t >> 6, lane = t & 63;
  int m31 = lane & 31, hf = lane >> 5;  // 32-row index, half
  int q0 = qt * 128;
  int srow = lane >> 3;
  int schunk = (lane & 7) ^ srow;

  // Q B-frags: loop-invariant, direct from global. B[k=d][n=q]: n=m31, k=8*hf+j
  short8 qf[4];
  {
    size_t qrow = (size_t)(b * S_LEN + q0 + w * 32 + m31) * NQKV + h * DHEAD;
#pragma unroll
    for (int kk = 0; kk < 4; ++kk)
      qf[kk] = *(const short8*)&QKV[qrow + kk * 16 + hf * 8];
  }

  float lsum = 0.f;                    // l for q = m31 (this lane's column)
  f32x16 o[2] = {};                    // O tiles: d in {nt*32 + m31}
  size_t vtbase = (size_t)((b * NH + h) * DHEAD) * S_LEN;
  size_t kbase0 = (size_t)(b * S_LEN) * NQKV + 768 + h * DHEAD;
  const float* mrow = mask2 + (size_t)b * S_LEN;

  // prologue: stage tile 0 into buffer 0
#pragma unroll
  for (int it = 0; it < 2; ++it) {
    int rb = w * 16 + it * 8;
    int r = rb + srow;
    gl2lds16(&QKV[kbase0 + (size_t)r * NQKV + schunk * 8], &Ks[0][rb][0]);
    gl2lds16(&Vt[vtbase + (size_t)r * S_LEN + schunk * 8], &Vts[0][rb][0]);
  }

  int buf = 0;
  for (int kt = 0; kt < S_LEN / 64; ++kt) {
    int k0 = kt * 64;
    __syncthreads();  // tile kt resident (vmcnt drained); prev compute done

    // prefetch next tile into buf^1 (clamped redundant reload on last iter)
    {
      int ktn = (kt + 1 < S_LEN / 64) ? (kt + 1) : kt;
      int k0n = ktn * 64;
#pragma unroll
      for (int it = 0; it < 2; ++it) {
        int rb = w * 16 + it * 8;
        int r = rb + srow;
        gl2lds16(&QKV[kbase0 + (size_t)(k0n + r) * NQKV + schunk * 8], &Ks[buf ^ 1][rb][0]);
        gl2lds16(&Vt[vtbase + (size_t)r * S_LEN + k0n + schunk * 8], &Vts[buf ^ 1][rb][0]);
      }
    }

    // S^T[key][q] = K·Q^T: A=K rows (2 mt tiles of 32 keys), B=qf. k-dim=64 (4 kk)
    f32x16 s[2] = {};
    __builtin_amdgcn_s_setprio(1);
#pragma unroll
    for (int kk = 0; kk < 4; ++kk)
#pragma unroll
      for (int mt = 0; mt < 2; ++mt) {
        int r = mt * 32 + m31;
        short8 ak = *(const short8*)&Ks[buf][r][((kk * 2 + hf) ^ (r & 7)) * 8];
        s[mt] = __builtin_amdgcn_mfma_f32_32x32x16_bf16(ak, qf[kk], s[mt], 0, 0, 0);
      }
    __builtin_amdgcn_s_setprio(0);

    // p = 2^(s + mask2) (everything pre-scaled by log2e)
    // key = 32mt + 8g + 4hf + i ; q = m31. Pack to bf16 pairs in-register.
    unsigned pw[2][4][2];
#pragma unroll
    for (int mt = 0; mt < 2; ++mt)
#pragma unroll
      for (int gg = 0; gg < 4; ++gg) {
        float4 mv = *(const float4*)&mrow[k0 + mt * 32 + gg * 8 + hf * 4];
        float p0 = fexp2(s[mt][gg * 4 + 0] + mv.x);
        float p1 = fexp2(s[mt][gg * 4 + 1] + mv.y);
        float p2 = fexp2(s[mt][gg * 4 + 2] + mv.z);
        float p3 = fexp2(s[mt][gg * 4 + 3] + mv.w);
        lsum += (p0 + p1) + (p2 + p3);
        pw[mt][gg][0] = cvtpk(p0, p1);  // keys 32mt+8g+4hf+{0,1}
        pw[mt][gg][1] = cvtpk(p2, p3);  // keys 32mt+8g+4hf+{2,3}
      }

    // Build PV A-frags via permlane32_swap; O[q][d] += P·V
    // frag(kk) lane(hf) needs keys 16kk+8hf+{0..7}; swap merges lane-halves.
#pragma unroll
    for (int mt = 0; mt < 2; ++mt)
#pragma unroll
      for (int kk2 = 0; kk2 < 2; ++kk2) {
        unsigned a0 = pw[mt][2 * kk2][0], b0 = pw[mt][2 * kk2 + 1][0];
        unsigned a1 = pw[mt][2 * kk2][1], b1 = pw[mt][2 * kk2 + 1][1];
        plswap(a0, b0);  // a0=[keys+0,1 | +8,9]   b0=[keys+4,5 | +12,13]
        plswap(a1, b1);  // a1=[keys+2,3 | +10,11] b1=[keys+6,7 | +14,15]
        union { unsigned u[4]; short8 v; } fr;
        fr.u[0] = a0; fr.u[1] = a1; fr.u[2] = b0; fr.u[3] = b1;
        int kk = mt * 2 + kk2;
        __builtin_amdgcn_s_setprio(1);
#pragma unroll
        for (int nt = 0; nt < 2; ++nt) {
          int r = nt * 32 + m31;
          short8 bvv = *(const short8*)&Vts[buf][r][((kk * 2 + hf) ^ (r & 7)) * 8];
          o[nt] = __builtin_amdgcn_mfma_f32_32x32x16_bf16(fr.v, bvv, o[nt], 0, 0, 0);
        }
        __builtin_amdgcn_s_setprio(0);
      }

    buf ^= 1;
  }

  // final l for q=m31: own half + partner half, once
  lsum += __shfl_xor(lsum, 32, 64);
  float inv = 1.0f / lsum;
  // broadcast inv to C-layout rows: row q = (r&3) + 8*(r>>2) + 4*hf
  float lv[16];
#pragma unroll
  for (int r = 0; r < 16; ++r)
    lv[r] = __shfl(inv, (r & 3) + 8 * (r >> 2) + 4 * hf, 64);

  for (int nt = 0; nt < 2; ++nt)
    for (int r = 0; r < 16; ++r) {
      int qrow = (r & 3) + 8 * (r >> 2) + 4 * hf;
      int q = q0 + w * 32 + qrow;
      out[(size_t)(b * S_LEN + q) * DMODEL + h * DHEAD + nt * 32 + m31] = o[nt][r] * lv[r];
    }
}

extern "C" void kernel_launch(void* const* d_in, const int* in_sizes, int n_in,
                              void* d_out, int out_size, void* d_ws, size_t ws_size,
                              hipStream_t stream) {
  const float* hs   = (const float*)d_in[0];
  const float* mask = (const float*)d_in[1];
  const float* Wq   = (const float*)d_in[2];
  const float* bq   = (const float*)d_in[3];
  const float* Wk   = (const float*)d_in[4];
  const float* bk   = (const float*)d_in[5];
  const float* Wv   = (const float*)d_in[6];
  const float* bv   = (const float*)d_in[7];
  float* out = (float*)d_out;

  char* ws = (char*)d_ws;
  const size_t XB_BYTES   = (size_t)MROWS * DMODEL * 2;
  const size_t QKV_BYTES  = (size_t)MROWS * NQKV * 2;
  const size_t WALL_BYTES = (size_t)NQKV * DMODEL * 2;
  unsigned short* Xb    = (unsigned short*)ws;
  unsigned short* QKV   = (unsigned short*)(ws + XB_BYTES);
  unsigned short* Wall  = (unsigned short*)(ws + XB_BYTES + QKV_BYTES);
  float*          mask2 = (float*)(ws + XB_BYTES + QKV_BYTES + WALL_BYTES);
  unsigned short* Vtg   = Xb;  // Xb dead after qkv_gemm

  const int NX = MROWS * DMODEL / 4;
  const int NW = DMODEL * DMODEL / 4;
  const int NM = (BATCH * S_LEN) / 4;
  int nprep = NX + 3 * NW + NM;
  prep_kernel<<<(nprep + 255) / 256, 256, 0, stream>>>(hs, Wq, Wk, Wv, mask, Xb, Wall, mask2);

  qkv_gemm<<<1152, 256, 0, stream>>>(Xb, Wall, bq, bk, bv, QKV);

  v_transpose<<<dim3(S_LEN / 64, NH, BATCH), 256, 0, stream>>>(QKV, Vtg);

  flash_attn<<<768, 256, 0, stream>>>(QKV, Vtg, mask2, out);
}

// Round 6
// 220.256 us; speedup vs baseline: 1.8637x; 1.0375x over previous
//
#include <hip/hip_runtime.h>

#define S_LEN 2048
#define DMODEL 768
#define NH 12
#define DHEAD 64
#define BATCH 4
#define MROWS (BATCH * S_LEN)  // 8192
#define NQKV 2304              // 3*DMODEL
#define NQK 1536               // packed Q+K row stride
#define LOG2E 1.4426950408889634f

using short8 = __attribute__((ext_vector_type(8))) short;
using f32x4  = __attribute__((ext_vector_type(4))) float;
using f32x16 = __attribute__((ext_vector_type(16))) float;

typedef const __attribute__((address_space(1))) void* gas_ptr;
typedef __attribute__((address_space(3))) void* las_ptr;

__device__ __forceinline__ void gl2lds16(const void* g, void* l) {
  __builtin_amdgcn_global_load_lds((gas_ptr)(unsigned long long)g,
                                   (las_ptr)(unsigned int)(unsigned long long)l,
                                   16, 0, 0);
}

// 2^x via raw v_exp_f32
__device__ __forceinline__ float fexp2(float x) {
  float r;
  asm("v_exp_f32 %0, %1" : "=v"(r) : "v"(x));
  return r;
}

// packed f32x2 -> bf16x2 (RNE), lo in [15:0]
__device__ __forceinline__ unsigned cvtpk(float lo, float hi) {
  unsigned r;
  asm("v_cvt_pk_bf16_f32 %0, %1, %2" : "=v"(r) : "v"(lo), "v"(hi));
  return r;
}

// swap a.hi32lanes <-> b.lo32lanes
__device__ __forceinline__ void plswap(unsigned &a, unsigned &b) {
  asm("v_permlane32_swap_b32 %0, %1" : "+v"(a), "+v"(b));
}

// Fused prep: fp32->bf16 for X and the 3 W's, mask -> (mask-10)*log2e
__global__ __launch_bounds__(256) void prep_kernel(
    const float* __restrict__ hs, const float* __restrict__ Wq,
    const float* __restrict__ Wk, const float* __restrict__ Wv,
    const float* __restrict__ mask,
    unsigned short* __restrict__ Xb, unsigned short* __restrict__ Wall,
    float* __restrict__ mask2)
{
  const int NX = MROWS * DMODEL / 4;
  const int NW = DMODEL * DMODEL / 4;
  const int NM = (BATCH * S_LEN) / 4;
  int i = blockIdx.x * 256 + threadIdx.x;
  if (i < NX) {
    float4 f = ((const float4*)hs)[i];
    uint2 o = { cvtpk(f.x, f.y), cvtpk(f.z, f.w) };
    ((uint2*)Xb)[i] = o;
  } else if (i < NX + 3 * NW) {
    int j = i - NX;
    int sec = j / NW, r = j - sec * NW;
    const float* src = (sec == 0) ? Wq : (sec == 1) ? Wk : Wv;
    float4 f = ((const float4*)src)[r];
    uint2 o = { cvtpk(f.x, f.y), cvtpk(f.z, f.w) };
    ((uint2*)(Wall + (size_t)sec * DMODEL * DMODEL))[r] = o;
  } else if (i < NX + 3 * NW + NM) {
    int r = i - NX - 3 * NW;
    float4 m = ((const float4*)mask)[r];
    float4 o = { (m.x - 10.f) * LOG2E, (m.y - 10.f) * LOG2E,
                 (m.z - 10.f) * LOG2E, (m.w - 10.f) * LOG2E };
    ((float4*)mask2)[r] = o;
  }
}

// Out: Q/K cols -> QK [8192][1536] (Q pre-scaled 1/8*log2e);
//      V cols   -> Vt [b][h][d][s] directly (v_transpose fused here).
// XCD-swizzled 1-D grid.
__global__ __launch_bounds__(256) void qkv_gemm(
    const unsigned short* __restrict__ Xb,   // [8192][768]
    const unsigned short* __restrict__ Wall, // [2304][768]
    const float* __restrict__ bq,
    const float* __restrict__ bk,
    const float* __restrict__ bv,
    unsigned short* __restrict__ QK,         // [8192][1536]
    unsigned short* __restrict__ Vt)         // [4*12*64][2048]
{
  __shared__ __align__(16) short As[128][64];
  __shared__ __align__(16) short Bs[128][64];

  // grid = 1152 = 8 xcd * 8 mlocal * 18 n
  int gid = blockIdx.x;
  int x = gid & 7;
  int j = gid >> 3;
  int mloc = j / 18;
  int ntile = j - mloc * 18;
  int m0 = (x * 8 + mloc) * 128;
  int n0 = ntile * 128;

  int t = threadIdx.x;
  int w = t >> 6, lane = t & 63, lg = lane >> 4, lc = lane & 15;
  int wr = (w >> 1) * 64, wc = (w & 1) * 64;

  int srow = lane >> 3;
  int schunk = (lane & 7) ^ srow;

  f32x4 acc[4][4] = {};

  for (int k0 = 0; k0 < DMODEL; k0 += 64) {
    __syncthreads();
    for (int it = 0; it < 4; ++it) {
      int rb = w * 32 + it * 8;
      int r = rb + srow;
      gl2lds16(&Xb[(size_t)(m0 + r) * DMODEL + k0 + schunk * 8], &As[rb][0]);
      gl2lds16(&Wall[(size_t)(n0 + r) * DMODEL + k0 + schunk * 8], &Bs[rb][0]);
    }
    __syncthreads();
    for (int ks = 0; ks < 2; ++ks) {
      short8 a[4], b[4];
      for (int mt = 0; mt < 4; ++mt)
        a[mt] = *(const short8*)&As[wr + mt * 16 + lc][(((ks * 4 + lg) ^ (lc & 7))) * 8];
      for (int nt = 0; nt < 4; ++nt)
        b[nt] = *(const short8*)&Bs[wc + nt * 16 + lc][(((ks * 4 + lg) ^ (lc & 7))) * 8];
      for (int mt = 0; mt < 4; ++mt)
        for (int nt = 0; nt < 4; ++nt)
          acc[mt][nt] = __builtin_amdgcn_mfma_f32_16x16x32_bf16(a[mt], b[nt], acc[mt][nt], 0, 0, 0);
    }
  }

  if (n0 < 1536) {
    // ---- Q/K epilogue: row-major 2B stores into packed QK ----
    for (int nt = 0; nt < 4; ++nt) {
      int col = n0 + wc + nt * 16 + lc;
      float bb = (col < 768) ? bq[col] : bk[col - 768];
      float sc = (col < 768) ? (0.125f * LOG2E) : 1.0f;
      for (int mt = 0; mt < 4; ++mt) {
        int row = m0 + wr + mt * 16 + lg * 4;
        for (int i = 0; i < 4; ++i) {
          float v = (acc[mt][nt][i] + bb) * sc;
          QK[(size_t)(row + i) * NQK + col] = (unsigned short)cvtpk(v, v);
        }
      }
    }
  } else {
    // ---- V epilogue: write transposed directly to Vt [b][h][d][s] ----
    // acc rows i=0..3 are s-consecutive -> one 8B packed store each (mt,nt).
    int b2 = m0 >> 11;  // all 128 tile rows share one batch (2048/128=16)
    for (int nt = 0; nt < 4; ++nt) {
      int col = n0 + wc + nt * 16 + lc - 1536;  // 0..767 within V
      int h2 = col >> 6, dd = col & 63;
      float bb = bv[col];
      size_t vbase = ((size_t)(b2 * NH + h2) * DHEAD + dd) * S_LEN;
      for (int mt = 0; mt < 4; ++mt) {
        int row = m0 + wr + mt * 16 + lg * 4;
        int s = row & (S_LEN - 1);
        float v0 = acc[mt][nt][0] + bb;
        float v1 = acc[mt][nt][1] + bb;
        float v2 = acc[mt][nt][2] + bb;
        float v3 = acc[mt][nt][3] + bb;
        uint2 d2 = { cvtpk(v0, v1), cvtpk(v2, v3) };
        *(uint2*)&Vt[vbase + s] = d2;
      }
    }
  }
}

// Flash attention — R1-benched 94us body + XCD-swizzled grid (R5: 92us,
// FETCH 18.6MB). Only change this round: Q/K read from packed QK (stride 1536).
__global__ __launch_bounds__(256, 4) void flash_attn(
    const unsigned short* __restrict__ QK,   // [8192][1536]; Q pre-scaled log2e/8
    const unsigned short* __restrict__ Vt,   // [48*64][2048]
    const float* __restrict__ mask2,         // (mask-10)*log2e, [B][S]
    float* __restrict__ out)                 // [B][S][768]
{
  // grid = 768 = 8 xcd * 6 glocal * 16 qt ; group g=(b,h) pinned to one xcd
  int gid = blockIdx.x;
  int x = gid & 7;
  int j = gid >> 3;
  int gloc = j >> 4;
  int qt = j & 15;
  int g = gloc * 8 + x;
  int h = g % NH;
  int b = g / NH;

  __shared__ __align__(16) short Ks[2][64][64];    // swizzled [key][d]
  __shared__ __align__(16) short Vts[2][64][64];   // swizzled [d][key]

  int t = threadIdx.x, w = t >> 6, lane = t & 63;
  int m31 = lane & 31, hf = lane >> 5;  // 32-row index, half
  int q0 = qt * 128;
  int srow = lane >> 3;
  int schunk = (lane & 7) ^ srow;

  // Q B-frags: loop-invariant, direct from global. B[k=d][n=q]: n=m31, k=8*hf+j
  short8 qf[4];
  {
    size_t qrow = (size_t)(b * S_LEN + q0 + w * 32 + m31) * NQK + h * DHEAD;
#pragma unroll
    for (int kk = 0; kk < 4; ++kk)
      qf[kk] = *(const short8*)&QK[qrow + kk * 16 + hf * 8];
  }

  float lsum = 0.f;                    // l for q = m31 (this lane's column)
  f32x16 o[2] = {};                    // O tiles: d in {nt*32 + m31}
  size_t vtbase = (size_t)((b * NH + h) * DHEAD) * S_LEN;
  size_t kbase0 = (size_t)(b * S_LEN) * NQK + 768 + h * DHEAD;
  const float* mrow = mask2 + (size_t)b * S_LEN;

  // prologue: stage tile 0 into buffer 0
#pragma unroll
  for (int it = 0; it < 2; ++it) {
    int rb = w * 16 + it * 8;
    int r = rb + srow;
    gl2lds16(&QK[kbase0 + (size_t)r * NQK + schunk * 8], &Ks[0][rb][0]);
    gl2lds16(&Vt[vtbase + (size_t)r * S_LEN + schunk * 8], &Vts[0][rb][0]);
  }

  int buf = 0;
  for (int kt = 0; kt < S_LEN / 64; ++kt) {
    int k0 = kt * 64;
    __syncthreads();  // tile kt resident (vmcnt drained); prev compute done

    // prefetch next tile into buf^1 (clamped redundant reload on last iter)
    {
      int ktn = (kt + 1 < S_LEN / 64) ? (kt + 1) : kt;
      int k0n = ktn * 64;
#pragma unroll
      for (int it = 0; it < 2; ++it) {
        int rb = w * 16 + it * 8;
        int r = rb + srow;
        gl2lds16(&QK[kbase0 + (size_t)(k0n + r) * NQK + schunk * 8], &Ks[buf ^ 1][rb][0]);
        gl2lds16(&Vt[vtbase + (size_t)r * S_LEN + k0n + schunk * 8], &Vts[buf ^ 1][rb][0]);
      }
    }

    // S^T[key][q] = K·Q^T: A=K rows (2 mt tiles of 32 keys), B=qf. k-dim=64 (4 kk)
    f32x16 s[2] = {};
    __builtin_amdgcn_s_setprio(1);
#pragma unroll
    for (int kk = 0; kk < 4; ++kk)
#pragma unroll
      for (int mt = 0; mt < 2; ++mt) {
        int r = mt * 32 + m31;
        short8 ak = *(const short8*)&Ks[buf][r][((kk * 2 + hf) ^ (r & 7)) * 8];
        s[mt] = __builtin_amdgcn_mfma_f32_32x32x16_bf16(ak, qf[kk], s[mt], 0, 0, 0);
      }
    __builtin_amdgcn_s_setprio(0);

    // p = 2^(s + mask2) (everything pre-scaled by log2e)
    // key = 32mt + 8g + 4hf + i ; q = m31. Pack to bf16 pairs in-register.
    unsigned pw[2][4][2];
#pragma unroll
    for (int mt = 0; mt < 2; ++mt)
#pragma unroll
      for (int gg = 0; gg < 4; ++gg) {
        float4 mv = *(const float4*)&mrow[k0 + mt * 32 + gg * 8 + hf * 4];
        float p0 = fexp2(s[mt][gg * 4 + 0] + mv.x);
        float p1 = fexp2(s[mt][gg * 4 + 1] + mv.y);
        float p2 = fexp2(s[mt][gg * 4 + 2] + mv.z);
        float p3 = fexp2(s[mt][gg * 4 + 3] + mv.w);
        lsum += (p0 + p1) + (p2 + p3);
        pw[mt][gg][0] = cvtpk(p0, p1);  // keys 32mt+8g+4hf+{0,1}
        pw[mt][gg][1] = cvtpk(p2, p3);  // keys 32mt+8g+4hf+{2,3}
      }

    // Build PV A-frags via permlane32_swap; O[q][d] += P·V
    // frag(kk) lane(hf) needs keys 16kk+8hf+{0..7}; swap merges lane-halves.
#pragma unroll
    for (int mt = 0; mt < 2; ++mt)
#pragma unroll
      for (int kk2 = 0; kk2 < 2; ++kk2) {
        unsigned a0 = pw[mt][2 * kk2][0], b0 = pw[mt][2 * kk2 + 1][0];
        unsigned a1 = pw[mt][2 * kk2][1], b1 = pw[mt][2 * kk2 + 1][1];
        plswap(a0, b0);  // a0=[keys+0,1 | +8,9]   b0=[keys+4,5 | +12,13]
        plswap(a1, b1);  // a1=[keys+2,3 | +10,11] b1=[keys+6,7 | +14,15]
        union { unsigned u[4]; short8 v; } fr;
        fr.u[0] = a0; fr.u[1] = a1; fr.u[2] = b0; fr.u[3] = b1;
        int kk = mt * 2 + kk2;
        __builtin_amdgcn_s_setprio(1);
#pragma unroll
        for (int nt = 0; nt < 2; ++nt) {
          int r = nt * 32 + m31;
          short8 bvv = *(const short8*)&Vts[buf][r][((kk * 2 + hf) ^ (r & 7)) * 8];
          o[nt] = __builtin_amdgcn_mfma_f32_32x32x16_bf16(fr.v, bvv, o[nt], 0, 0, 0);
        }
        __builtin_amdgcn_s_setprio(0);
      }

    buf ^= 1;
  }

  // final l for q=m31: own half + partner half, once
  lsum += __shfl_xor(lsum, 32, 64);
  float inv = 1.0f / lsum;
  // broadcast inv to C-layout rows: row q = (r&3) + 8*(r>>2) + 4*hf
  float lv[16];
#pragma unroll
  for (int r = 0; r < 16; ++r)
    lv[r] = __shfl(inv, (r & 3) + 8 * (r >> 2) + 4 * hf, 64);

  for (int nt = 0; nt < 2; ++nt)
    for (int r = 0; r < 16; ++r) {
      int qrow = (r & 3) + 8 * (r >> 2) + 4 * hf;
      int q = q0 + w * 32 + qrow;
      out[(size_t)(b * S_LEN + q) * DMODEL + h * DHEAD + nt * 32 + m31] = o[nt][r] * lv[r];
    }
}

extern "C" void kernel_launch(void* const* d_in, const int* in_sizes, int n_in,
                              void* d_out, int out_size, void* d_ws, size_t ws_size,
                              hipStream_t stream) {
  const float* hs   = (const float*)d_in[0];
  const float* mask = (const float*)d_in[1];
  const float* Wq   = (const float*)d_in[2];
  const float* bq   = (const float*)d_in[3];
  const float* Wk   = (const float*)d_in[4];
  const float* bk   = (const float*)d_in[5];
  const float* Wv   = (const float*)d_in[6];
  const float* bv   = (const float*)d_in[7];
  float* out = (float*)d_out;

  char* ws = (char*)d_ws;
  const size_t XB_BYTES   = (size_t)MROWS * DMODEL * 2;   // 12.58 MB
  const size_t QK_BYTES   = (size_t)MROWS * NQK * 2;      // 25.17 MB
  const size_t VT_BYTES   = (size_t)BATCH * NH * DHEAD * S_LEN * 2;  // 12.58 MB
  const size_t WALL_BYTES = (size_t)NQKV * DMODEL * 2;    // 3.54 MB
  unsigned short* Xb    = (unsigned short*)ws;
  unsigned short* QK    = (unsigned short*)(ws + XB_BYTES);
  unsigned short* Vtg   = (unsigned short*)(ws + XB_BYTES + QK_BYTES);
  unsigned short* Wall  = (unsigned short*)(ws + XB_BYTES + QK_BYTES + VT_BYTES);
  float*          mask2 = (float*)(ws + XB_BYTES + QK_BYTES + VT_BYTES + WALL_BYTES);

  const int NX = MROWS * DMODEL / 4;
  const int NW = DMODEL * DMODEL / 4;
  const int NM = (BATCH * S_LEN) / 4;
  int nprep = NX + 3 * NW + NM;
  prep_kernel<<<(nprep + 255) / 256, 256, 0, stream>>>(hs, Wq, Wk, Wv, mask, Xb, Wall, mask2);

  qkv_gemm<<<1152, 256, 0, stream>>>(Xb, Wall, bq, bk, bv, QK, Vtg);

  flash_attn<<<768, 256, 0, stream>>>(QK, Vtg, mask2, out);
}